// Round 1
// baseline (29000.159 us; speedup 1.0000x reference)
//
#include <hip/hip_runtime.h>
#include <math.h>

// ---------------- constants ----------------
#define Bz    8
#define Tt    8192
#define NEU   256
#define Dm    1024
#define Hh    16
#define Ll    8
#define FFd   4096
#define HDd   64
#define KL    14
#define BLANK 41
#define DIPd  40
#define GKS   20
#define TmD   8193              // T+1 after even-kernel conv
#define Ss    585               // Tm // KL
#define PEIN  3584              // KL*NEU
#define MTOK  (Bz * Ss)         // 4680

#define NEG_INF (-3.4e38f)

// ---------------- gaussian smoothing along time ----------------
// out[b,t,c] = sum_j neural[b, t-10+j, c] * w[j], t in [0, Tm)
__global__ __launch_bounds__(256) void smooth_kernel(
    const float* __restrict__ neural, float* __restrict__ out) {
  const int b = blockIdx.y, t = blockIdx.x, c = threadIdx.x;
  float w[GKS];
  float wsum = 0.f;
#pragma unroll
  for (int j = 0; j < GKS; j++) {
    float e = (j - 9.5f) * 0.5f;      // (x-mean)/sigma, sigma=2
    w[j] = expf(-0.5f * e * e);
    wsum += w[j];
  }
  float acc = 0.f;
#pragma unroll
  for (int j = 0; j < GKS; j++) {
    int tt = t - GKS / 2 + j;
    if (tt >= 0 && tt < Tt) acc += neural[((size_t)b * Tt + tt) * NEU + c] * w[j];
  }
  out[((size_t)b * TmD + t) * NEU + c] = acc / wsum;
}

// ---------------- day linear + softsign + length mask (in place) ----------------
__global__ __launch_bounds__(256) void day_kernel(
    float* __restrict__ x, const float* __restrict__ dayW,
    const float* __restrict__ dayB, const int* __restrict__ day_idx,
    const int* __restrict__ lengths) {
  const int b = blockIdx.y;
  const int t0 = blockIdx.x * 8;
  const int c = threadIdx.x;
  const int di = day_idx[b];
  const int len = lengths[b];
  const float* W = dayW + (size_t)di * NEU * NEU;
  __shared__ float rows[8][NEU];
  float* xb = x + ((size_t)b * TmD + t0) * NEU;
  const int nr = min(8, TmD - t0);
  for (int r = 0; r < nr; r++) rows[r][c] = xb[(size_t)r * NEU + c];
  __syncthreads();
  float acc[8];
  const float bb = dayB[(size_t)di * NEU + c];
#pragma unroll
  for (int r = 0; r < 8; r++) acc[r] = bb;
  for (int d = 0; d < NEU; d++) {
    const float w = W[(size_t)d * NEU + c];
#pragma unroll
    for (int r = 0; r < 8; r++) acc[r] += rows[r][d] * w;
  }
  for (int r = 0; r < nr; r++) {
    const int t = t0 + r;
    float v = acc[r] / (1.f + fabsf(acc[r]));   // softsign
    xb[(size_t)r * NEU + c] = (t < len) ? v : 0.f;
  }
}

// ---------------- generic layernorm ----------------
// src row addressing: base = (row/inner)*strideA + (row%inner)*strideB
// (inner=rows, strideA=0, strideB=N for plain contiguous rows)
__global__ __launch_bounds__(256) void ln_kernel(
    const float* __restrict__ in, const float* __restrict__ w,
    const float* __restrict__ bias, float* __restrict__ out,
    int N, float eps, int inner, long strideA, long strideB) {
  const int row = blockIdx.x;
  const float* src = in + (size_t)(row / inner) * strideA + (size_t)(row % inner) * strideB;
  float* dst = out + (size_t)row * N;
  const int tid = threadIdx.x;
  float s = 0.f, ss = 0.f;
  for (int i = tid; i < N; i += 256) {
    float v = src[i];
    s += v; ss += v * v;
  }
  __shared__ float rs[256], rss[256];
  rs[tid] = s; rss[tid] = ss;
  __syncthreads();
  for (int k = 128; k > 0; k >>= 1) {
    if (tid < k) { rs[tid] += rs[tid + k]; rss[tid] += rss[tid + k]; }
    __syncthreads();
  }
  const float mean = rs[0] / N;
  const float var = rss[0] / N - mean * mean;
  const float rstd = rsqrtf(var + eps);
  for (int i = tid; i < N; i += 256)
    dst[i] = (src[i] - mean) * rstd * w[i] + bias[i];
}

// ---------------- general fp32 GEMM: C = epi(A[M,K] @ B[K,N] + bias) ----------------
// epi 0: store   1: gelu-store   2: C += r   3: C += (query padded ? 0 : r)
__global__ __launch_bounds__(256) void gemm_f32(
    const float* __restrict__ A, const float* __restrict__ Bm,
    const float* __restrict__ bias, float* __restrict__ C,
    int M, int N, int K, int epi, const int* __restrict__ eff) {
  __shared__ __align__(16) float As[16][64];
  __shared__ __align__(16) float Bs[16][64];
  const int tid = threadIdx.x;
  const int tx = tid & 15, ty = tid >> 4;
  const int bm = blockIdx.x * 64, bn = blockIdx.y * 64;
  float acc[4][4] = {};
  const int am = tid >> 2;
  const int ak = (tid & 3) * 4;
  const int bk = tid >> 4;
  const int bnn = (tid & 15) * 4;
  for (int k0 = 0; k0 < K; k0 += 16) {
    {
      const int gm = bm + am;
      const float* ap = A + (size_t)gm * K + k0 + ak;
#pragma unroll
      for (int i = 0; i < 4; i++) {
        const int gk = k0 + ak + i;
        As[ak + i][am] = (gm < M && gk < K) ? ap[i] : 0.f;
      }
    }
    {
      const int gk = k0 + bk;
      const float* bp = Bm + (size_t)gk * N + bn + bnn;
#pragma unroll
      for (int i = 0; i < 4; i++) {
        const int gn = bn + bnn + i;
        Bs[bk][bnn + i] = (gk < K && gn < N) ? bp[i] : 0.f;
      }
    }
    __syncthreads();
#pragma unroll
    for (int kk = 0; kk < 16; kk++) {
      const float4 av = *reinterpret_cast<const float4*>(&As[kk][ty * 4]);
      const float4 bv = *reinterpret_cast<const float4*>(&Bs[kk][tx * 4]);
      const float a[4] = {av.x, av.y, av.z, av.w};
      const float b[4] = {bv.x, bv.y, bv.z, bv.w};
#pragma unroll
      for (int i = 0; i < 4; i++)
#pragma unroll
        for (int j = 0; j < 4; j++) acc[i][j] += a[i] * b[j];
    }
    __syncthreads();
  }
#pragma unroll
  for (int i = 0; i < 4; i++) {
    const int gm = bm + ty * 4 + i;
    if (gm >= M) continue;
    bool masked = false;
    if (epi == 3) masked = ((gm % Ss) >= eff[gm / Ss]);
#pragma unroll
    for (int j = 0; j < 4; j++) {
      const int gn = bn + tx * 4 + j;
      if (gn >= N) continue;
      float r = acc[i][j] + bias[gn];
      const size_t o = (size_t)gm * N + gn;
      if (epi == 0) C[o] = r;
      else if (epi == 1) C[o] = 0.5f * r * (1.f + erff(r * 0.70710678118654752f));
      else if (epi == 2) C[o] += r;
      else C[o] += masked ? 0.f : r;
    }
  }
}

// ---------------- attention: one block per (q, h, b) ----------------
// qkv layout: [B*S, 3*D]; q at col h*64+d, k at D+..., v at 2D+...
// out layout: [B*S, D] with d = h*64 + hd (matches reference transpose-back)
__global__ __launch_bounds__(128) void attn_kernel(
    const float* __restrict__ qkv, float* __restrict__ out,
    const int* __restrict__ eff) {
  const int q = blockIdx.x, h = blockIdx.y, b = blockIdx.z;
  const int tid = threadIdx.x;
  __shared__ __align__(16) float sq[HDd];
  __shared__ float sc[Ss];
  __shared__ float rbuf[128];
  const size_t qbase = ((size_t)b * Ss + q) * (3 * Dm) + h * HDd;
  if (tid < HDd) sq[tid] = qkv[qbase + tid];
  __syncthreads();
  const int jmax = min(q, eff[b] - 1);   // causal + key-pad exclusion (exp underflow-exact)
  float lmax = NEG_INF;
  for (int j = tid; j <= jmax; j += 128) {
    const float4* kp = reinterpret_cast<const float4*>(
        qkv + ((size_t)b * Ss + j) * (3 * Dm) + Dm + h * HDd);
    const float4* qp = reinterpret_cast<const float4*>(sq);
    float d = 0.f;
#pragma unroll
    for (int x = 0; x < HDd / 4; x++) {
      const float4 kv = kp[x], qv = qp[x];
      d += qv.x * kv.x + qv.y * kv.y + qv.z * kv.z + qv.w * kv.w;
    }
    d *= 0.125f;                // 1/sqrt(64)
    sc[j] = d;
    lmax = fmaxf(lmax, d);
  }
  rbuf[tid] = lmax;
  __syncthreads();
  for (int k = 64; k > 0; k >>= 1) {
    if (tid < k) rbuf[tid] = fmaxf(rbuf[tid], rbuf[tid + k]);
    __syncthreads();
  }
  const float m = rbuf[0];
  __syncthreads();
  float lsum = 0.f;
  for (int j = tid; j <= jmax; j += 128) {
    const float p = expf(sc[j] - m);
    sc[j] = p;
    lsum += p;
  }
  rbuf[tid] = lsum;
  __syncthreads();
  for (int k = 64; k > 0; k >>= 1) {
    if (tid < k) rbuf[tid] += rbuf[tid + k];
    __syncthreads();
  }
  const float inv = 1.f / rbuf[0];
  __syncthreads();
  if (tid < HDd) {
    float acc = 0.f;
    const float* vp = qkv + (size_t)b * Ss * (3 * Dm) + 2 * Dm + h * HDd + tid;
    for (int j = 0; j <= jmax; j++) acc += sc[j] * vp[(size_t)j * (3 * Dm)];
    out[((size_t)b * Ss + q) * Dm + h * HDd + tid] = acc * inv;
  }
}

// ---------------- log_softmax over 41, optional probs out ----------------
__global__ __launch_bounds__(64) void lsm41_kernel(
    const float* __restrict__ in, float* __restrict__ lp,
    float* __restrict__ probs) {
  const int row = blockIdx.x, t = threadIdx.x;
  const float z = (t < BLANK) ? in[(size_t)row * BLANK + t] : NEG_INF;
  float m = z;
#pragma unroll
  for (int off = 32; off; off >>= 1) m = fmaxf(m, __shfl_xor(m, off));
  float s = (t < BLANK) ? expf(z - m) : 0.f;
#pragma unroll
  for (int off = 32; off; off >>= 1) s += __shfl_xor(s, off);
  const float l = z - m - logf(s);
  if (t < BLANK) {
    lp[(size_t)row * BLANK + t] = l;
    if (probs) probs[(size_t)row * BLANK + t] = expf(l);
  }
}

// ---------------- diphone marginalization ----------------
// out = u - lse(u), u[c] = logaddexp(lse_row_c(z), lse_col_c(z))
// (global LSE and log2 cancel in the final normalization)
__global__ __launch_bounds__(64) void diphone_kernel(
    const float* __restrict__ in, float* __restrict__ out) {
  __shared__ float z[DIPd * DIPd];
  __shared__ float u[DIPd];
  const int row = blockIdx.x, t = threadIdx.x;
  for (int i = t; i < DIPd * DIPd; i += 64) z[i] = in[(size_t)row * (DIPd * DIPd) + i];
  __syncthreads();
  if (t < DIPd) {
    float m1 = NEG_INF;
    for (int j = 0; j < DIPd; j++) m1 = fmaxf(m1, z[t * DIPd + j]);
    float s1 = 0.f;
    for (int j = 0; j < DIPd; j++) s1 += expf(z[t * DIPd + j] - m1);
    const float lr = m1 + logf(s1);
    float m2 = NEG_INF;
    for (int j = 0; j < DIPd; j++) m2 = fmaxf(m2, z[j * DIPd + t]);
    float s2 = 0.f;
    for (int j = 0; j < DIPd; j++) s2 += expf(z[j * DIPd + t] - m2);
    const float lc = m2 + logf(s2);
    const float mx = fmaxf(lr, lc), mn = fminf(lr, lc);
    u[t] = mx + log1pf(expf(mn - mx));
  }
  __syncthreads();
  const float v = (t < DIPd) ? u[t] : NEG_INF;
  float m = v;
#pragma unroll
  for (int off = 32; off; off >>= 1) m = fmaxf(m, __shfl_xor(m, off));
  float s = (t < DIPd) ? expf(v - m) : 0.f;
#pragma unroll
  for (int off = 32; off; off >>= 1) s += __shfl_xor(s, off);
  const float lse = m + logf(s);
  if (t < DIPd) out[(size_t)row * DIPd + t] = v - lse;
}

// ---------------- eff = max(lengths // KL, 1) ----------------
__global__ void eff_kernel(const int* __restrict__ lengths, int* __restrict__ eff) {
  const int t = threadIdx.x;
  if (t < Bz) {
    int e = lengths[t] / KL;
    eff[t] = e < 1 ? 1 : e;
  }
}

// ---------------- host ----------------
extern "C" void kernel_launch(void* const* d_in, const int* in_sizes, int n_in,
                              void* d_out, int out_size, void* d_ws, size_t ws_size,
                              hipStream_t stream) {
  (void)in_sizes; (void)n_in; (void)out_size; (void)ws_size;
  const float* neural     = (const float*)d_in[0];
  const int*   lengths    = (const int*)d_in[1];
  const int*   day_idx    = (const int*)d_in[2];
  const float* day_W      = (const float*)d_in[3];
  const float* day_b      = (const float*)d_in[4];
  const float* pe_ln1_w   = (const float*)d_in[5];
  const float* pe_ln1_b   = (const float*)d_in[6];
  const float* pe_W       = (const float*)d_in[7];
  const float* pe_b       = (const float*)d_in[8];
  const float* pe_ln2_w   = (const float*)d_in[9];
  const float* pe_ln2_b   = (const float*)d_in[10];
  const float* ln_attn_w  = (const float*)d_in[11];
  const float* ln_attn_b  = (const float*)d_in[12];
  const float* qkv_W      = (const float*)d_in[13];
  const float* qkv_b      = (const float*)d_in[14];
  const float* attn_out_W = (const float*)d_in[15];
  const float* attn_out_b = (const float*)d_in[16];
  const float* ff_ln_w    = (const float*)d_in[17];
  const float* ff_ln_b    = (const float*)d_in[18];
  const float* fc1_W      = (const float*)d_in[19];
  const float* fc1_b      = (const float*)d_in[20];
  const float* fc2_W      = (const float*)d_in[21];
  const float* fc2_b      = (const float*)d_in[22];
  const float* final_ln_w = (const float*)d_in[23];
  const float* final_ln_b = (const float*)d_in[24];
  const float* ih_W       = (const float*)d_in[25];
  const float* ih_b       = (const float*)d_in[26];
  const float* fb_W       = (const float*)d_in[27];
  const float* fb_b       = (const float*)d_in[28];
  const float* fh_W       = (const float*)d_in[29];
  const float* fh_b       = (const float*)d_in[30];
  const float* dh_W       = (const float*)d_in[31];
  const float* dh_b       = (const float*)d_in[32];

  float* ws = (float*)d_ws;
  float* out = (float*)d_out;

  // workspace layout (floats)
  const size_t n_x   = (size_t)Bz * TmD * NEU;        // 16,779,264
  const size_t n_big = (size_t)MTOK * PEIN;           // 16,773,120 (>= MTOK*3D)
  const size_t n_tok = (size_t)MTOK * Dm;             // 4,792,320
  const size_t n_ff  = (size_t)MTOK * FFd;            // 19,169,280
  float* buf_x   = ws;
  float* buf_big = buf_x + n_x;        // patch-LN out, later qkv
  float* buf_h   = buf_big + n_big;
  float* buf_a   = buf_h + n_tok;
  float* buf_ao  = buf_a + n_tok;
  float* buf_ff  = buf_ao + n_tok;
  float* buf_blank = buf_ff;           // overlays ff (dead at use time)
  float* buf_probs = buf_ff + 262144;
  float* buf_dip   = buf_ff + 524288;
  int* eff = (int*)(buf_ff + n_ff);

  auto gemm = [&](const float* A, const float* Bm, const float* bias, float* C,
                  int M_, int N_, int K_, int epi) {
    dim3 g((M_ + 63) / 64, (N_ + 63) / 64);
    gemm_f32<<<g, 256, 0, stream>>>(A, Bm, bias, C, M_, N_, K_, epi, eff);
  };

  eff_kernel<<<1, 64, 0, stream>>>(lengths, eff);
  smooth_kernel<<<dim3(TmD, Bz), 256, 0, stream>>>(neural, buf_x);
  day_kernel<<<dim3((TmD + 7) / 8, Bz), 256, 0, stream>>>(buf_x, day_W, day_b, day_idx, lengths);
  // patch rows: base = b*(Tm*NEU) + s*(KL*NEU)
  ln_kernel<<<MTOK, 256, 0, stream>>>(buf_x, pe_ln1_w, pe_ln1_b, buf_big,
                                      PEIN, 1e-6f, Ss, (long)TmD * NEU, (long)KL * NEU);
  gemm(buf_big, pe_W, pe_b, buf_a, MTOK, Dm, PEIN, 0);
  ln_kernel<<<MTOK, 256, 0, stream>>>(buf_a, pe_ln2_w, pe_ln2_b, buf_h,
                                      Dm, 1e-6f, MTOK, 0L, (long)Dm);

  for (int i = 0; i < Ll; i++) {
    ln_kernel<<<MTOK, 256, 0, stream>>>(buf_h, ln_attn_w + (size_t)i * Dm,
                                        ln_attn_b + (size_t)i * Dm, buf_a,
                                        Dm, 1e-5f, MTOK, 0L, (long)Dm);
    gemm(buf_a, qkv_W + (size_t)i * Dm * 3 * Dm, qkv_b + (size_t)i * 3 * Dm,
         buf_big, MTOK, 3 * Dm, Dm, 0);
    attn_kernel<<<dim3(Ss, Hh, Bz), 128, 0, stream>>>(buf_big, buf_ao, eff);
    gemm(buf_ao, attn_out_W + (size_t)i * Dm * Dm, attn_out_b + (size_t)i * Dm,
         buf_h, MTOK, Dm, Dm, 3);
    ln_kernel<<<MTOK, 256, 0, stream>>>(buf_h, ff_ln_w + (size_t)i * Dm,
                                        ff_ln_b + (size_t)i * Dm, buf_a,
                                        Dm, 1e-5f, MTOK, 0L, (long)Dm);
    gemm(buf_a, fc1_W + (size_t)i * Dm * FFd, fc1_b + (size_t)i * FFd,
         buf_ff, MTOK, FFd, Dm, 1);
    gemm(buf_ff, fc2_W + (size_t)i * FFd * Dm, fc2_b + (size_t)i * Dm,
         buf_h, MTOK, Dm, FFd, 2);
    if (i == 3) {
      gemm(buf_h, ih_W, ih_b, buf_blank, MTOK, BLANK, Dm, 0);
      lsm41_kernel<<<MTOK, 64, 0, stream>>>(buf_blank, out + (size_t)MTOK * BLANK, buf_probs);
      gemm(buf_probs, fb_W, fb_b, buf_h, MTOK, Dm, BLANK, 2);
    }
  }

  ln_kernel<<<MTOK, 256, 0, stream>>>(buf_h, final_ln_w, final_ln_b, buf_a,
                                      Dm, 1e-5f, MTOK, 0L, (long)Dm);
  gemm(buf_a, fh_W, fh_b, buf_blank, MTOK, BLANK, Dm, 0);
  lsm41_kernel<<<MTOK, 64, 0, stream>>>(buf_blank, out, nullptr);
  gemm(buf_a, dh_W, dh_b, buf_dip, MTOK, DIPd * DIPd, Dm, 0);
  diphone_kernel<<<MTOK, 64, 0, stream>>>(buf_dip, out + (size_t)2 * MTOK * BLANK);
}

// Round 2
// 7635.056 us; speedup vs baseline: 3.7983x; 3.7983x over previous
//
#include <hip/hip_runtime.h>
#include <math.h>

// ---------------- constants ----------------
#define Bz    8
#define Tt    8192
#define NEU   256
#define Dm    1024
#define Hh    16
#define Ll    8
#define FFd   4096
#define HDd   64
#define KL    14
#define BLANK 41
#define DIPd  40
#define GKS   20
#define TmD   8193              // T+1 after even-kernel conv
#define Ss    585               // Tm // KL
#define PEIN  3584              // KL*NEU
#define MTOK  (Bz * Ss)         // 4680

#define NEG_INF (-3.4e38f)

typedef __attribute__((ext_vector_type(8))) short short8;
typedef __attribute__((ext_vector_type(4))) float f32x4;
typedef unsigned short ushort_t;

__device__ __forceinline__ float bf2f(ushort_t u) {
  union { unsigned int i; float f; } v; v.i = ((unsigned int)u) << 16; return v.f;
}
__device__ __forceinline__ ushort_t f2bf(float f) {
  union { float f; unsigned int i; } v; v.f = f;
  unsigned int x = v.i;
  if ((x & 0x7fffffffu) > 0x7f800000u) return 0x7fc0;
  return (ushort_t)((x + 0x7fffu + ((x >> 16) & 1u)) >> 16);
}

// ---------------- gaussian smoothing along time ----------------
__global__ __launch_bounds__(256) void smooth_kernel(
    const float* __restrict__ neural, float* __restrict__ out) {
  const int b = blockIdx.y, t = blockIdx.x, c = threadIdx.x;
  float w[GKS];
  float wsum = 0.f;
#pragma unroll
  for (int j = 0; j < GKS; j++) {
    float e = (j - 9.5f) * 0.5f;
    w[j] = expf(-0.5f * e * e);
    wsum += w[j];
  }
  float acc = 0.f;
#pragma unroll
  for (int j = 0; j < GKS; j++) {
    int tt = t - GKS / 2 + j;
    if (tt >= 0 && tt < Tt) acc += neural[((size_t)b * Tt + tt) * NEU + c] * w[j];
  }
  out[((size_t)b * TmD + t) * NEU + c] = acc / wsum;
}

// ---------------- day linear + softsign + length mask (in place) ----------------
__global__ __launch_bounds__(256) void day_kernel(
    float* __restrict__ x, const float* __restrict__ dayW,
    const float* __restrict__ dayB, const int* __restrict__ day_idx,
    const int* __restrict__ lengths) {
  const int b = blockIdx.y;
  const int t0 = blockIdx.x * 8;
  const int c = threadIdx.x;
  const int di = day_idx[b];
  const int len = lengths[b];
  const float* W = dayW + (size_t)di * NEU * NEU;
  __shared__ float rows[8][NEU];
  float* xb = x + ((size_t)b * TmD + t0) * NEU;
  const int nr = min(8, TmD - t0);
  for (int r = 0; r < nr; r++) rows[r][c] = xb[(size_t)r * NEU + c];
  __syncthreads();
  float acc[8];
  const float bb = dayB[(size_t)di * NEU + c];
#pragma unroll
  for (int r = 0; r < 8; r++) acc[r] = bb;
  for (int d = 0; d < NEU; d++) {
    const float w = W[(size_t)d * NEU + c];
#pragma unroll
    for (int r = 0; r < 8; r++) acc[r] += rows[r][d] * w;
  }
  for (int r = 0; r < nr; r++) {
    const int t = t0 + r;
    float v = acc[r] / (1.f + fabsf(acc[r]));
    xb[(size_t)r * NEU + c] = (t < len) ? v : 0.f;
  }
}

// ---------------- generic layernorm (fp32 in, fp32 or bf16 out) ----------------
__global__ __launch_bounds__(256) void ln_kernel(
    const float* __restrict__ in, const float* __restrict__ w,
    const float* __restrict__ bias, float* __restrict__ dstf,
    ushort_t* __restrict__ dstb,
    int N, float eps, int inner, long strideA, long strideB) {
  const int row = blockIdx.x;
  const float* src = in + (size_t)(row / inner) * strideA + (size_t)(row % inner) * strideB;
  const int tid = threadIdx.x;
  float s = 0.f, ss = 0.f;
  for (int i = tid; i < N; i += 256) {
    float v = src[i];
    s += v; ss += v * v;
  }
  __shared__ float rs[256], rss[256];
  rs[tid] = s; rss[tid] = ss;
  __syncthreads();
  for (int k = 128; k > 0; k >>= 1) {
    if (tid < k) { rs[tid] += rs[tid + k]; rss[tid] += rss[tid + k]; }
    __syncthreads();
  }
  const float mean = rs[0] / N;
  const float var = rss[0] / N - mean * mean;
  const float rstd = rsqrtf(var + eps);
  for (int i = tid; i < N; i += 256) {
    const float r = (src[i] - mean) * rstd * w[i] + bias[i];
    if (dstf) dstf[(size_t)row * N + i] = r;
    else dstb[(size_t)row * N + i] = f2bf(r);
  }
}

// ---------------- fp32 -> bf16 transpose (+ K zero-pad) ----------------
// in: [R][C] fp32, out: [C][Rp] bf16, out[c][r] = (r<R) ? in[r][c] : 0
__global__ __launch_bounds__(256) void convt_kernel(
    const float* __restrict__ in, ushort_t* __restrict__ out,
    int R, int C, int Rp) {
  __shared__ float t[32][33];
  const int r0 = blockIdx.x * 32, c0 = blockIdx.y * 32;
  const int tx = threadIdx.x, ty = threadIdx.y;   // 32 x 8
#pragma unroll
  for (int i = 0; i < 4; i++) {
    const int r = r0 + ty + i * 8, c = c0 + tx;
    t[ty + i * 8][tx] = (r < R && c < C) ? in[(size_t)r * C + c] : 0.f;
  }
  __syncthreads();
#pragma unroll
  for (int i = 0; i < 4; i++) {
    const int c = c0 + ty + i * 8, r = r0 + tx;
    if (c < C && r < Rp) out[(size_t)c * Rp + r] = f2bf(t[tx][ty + i * 8]);
  }
}

// ---------------- fp32 -> bf16 elementwise ----------------
__global__ __launch_bounds__(256) void f2b_kernel(
    const float* __restrict__ in, ushort_t* __restrict__ out, int n) {
  for (int i = blockIdx.x * 256 + threadIdx.x; i < n; i += gridDim.x * 256)
    out[i] = f2bf(in[i]);
}

// ---------------- bf16 MFMA GEMM: C = epi(A[M,K] @ Bt[N,K]^T + bias) ----------------
// epi 0: store fp32  1: gelu->bf16  2: fp32 C += r  3: masked fp32 C += r  4: store bf16
#define BM 128
#define BN 128
#define BKh 32
__global__ __launch_bounds__(256) void gemm_bf16(
    const ushort_t* __restrict__ A, const ushort_t* __restrict__ Bt,
    const float* __restrict__ bias, float* __restrict__ Cf,
    ushort_t* __restrict__ Cb, int M, int N, int K, int epi,
    const int* __restrict__ eff) {
  __shared__ short As[BM * BKh];   // [row][32] bf16, 64 B/row
  __shared__ short Bs[BN * BKh];   // [n]  [32] bf16
  const int tid = threadIdx.x;
  const int wave = tid >> 6, lane = tid & 63;
  const int lm = lane & 15, quad = lane >> 4;
  const int bm = blockIdx.x * BM, bn = blockIdx.y * BN;
  const int wm = (wave >> 1) * 64, wn = (wave & 1) * 64;

  f32x4 acc[4][4] = {};

  const int ldrow = lane >> 2;          // 0..15
  const int ldk = (lane & 3) * 8;       // k offset in halfs

  for (int k0 = 0; k0 < K; k0 += BKh) {
#pragma unroll
    for (int r = 0; r < 4; r++) {
      const int cid = wave * 4 + r;     // 0..15, wave-uniform
      if (cid < 8) {
        int row = bm + cid * 16 + ldrow;
        row = min(row, M - 1);
        const ushort_t* gp = A + (size_t)row * K + k0 + ldk;
        __builtin_amdgcn_global_load_lds(
            (const __attribute__((address_space(1))) unsigned int*)gp,
            (__attribute__((address_space(3))) unsigned int*)((char*)As + cid * 1024),
            16, 0, 0);
      } else {
        int row = bn + (cid - 8) * 16 + ldrow;
        row = min(row, N - 1);
        const ushort_t* gp = Bt + (size_t)row * K + k0 + ldk;
        __builtin_amdgcn_global_load_lds(
            (const __attribute__((address_space(1))) unsigned int*)gp,
            (__attribute__((address_space(3))) unsigned int*)((char*)Bs + (cid - 8) * 1024),
            16, 0, 0);
      }
    }
    __syncthreads();
    short8 af[4], bf[4];
#pragma unroll
    for (int mt = 0; mt < 4; mt++)
      af[mt] = *(const short8*)&As[(wm + mt * 16 + lm) * BKh + quad * 8];
#pragma unroll
    for (int nt = 0; nt < 4; nt++)
      bf[nt] = *(const short8*)&Bs[(wn + nt * 16 + lm) * BKh + quad * 8];
#pragma unroll
    for (int mt = 0; mt < 4; mt++)
#pragma unroll
      for (int nt = 0; nt < 4; nt++)
        acc[mt][nt] = __builtin_amdgcn_mfma_f32_16x16x32_bf16(
            af[mt], bf[nt], acc[mt][nt], 0, 0, 0);
    __syncthreads();
  }

#pragma unroll
  for (int mt = 0; mt < 4; mt++) {
#pragma unroll
    for (int r = 0; r < 4; r++) {
      const int gm = bm + wm + mt * 16 + quad * 4 + r;
      if (gm >= M) continue;
      bool masked = false;
      if (epi == 3) masked = ((gm % Ss) >= eff[gm / Ss]);
#pragma unroll
      for (int nt = 0; nt < 4; nt++) {
        const int gn = bn + wn + nt * 16 + lm;
        if (gn >= N) continue;
        const float v = acc[mt][nt][r] + bias[gn];
        const size_t o = (size_t)gm * N + gn;
        if (epi == 0) Cf[o] = v;
        else if (epi == 1) Cb[o] = f2bf(0.5f * v * (1.f + erff(v * 0.70710678118654752f)));
        else if (epi == 2) Cf[o] += v;
        else if (epi == 3) { if (!masked) Cf[o] += v; }
        else Cb[o] = f2bf(v);
      }
    }
  }
}

// ---------------- attention (bf16 qkv in, bf16 out) ----------------
__global__ __launch_bounds__(128) void attn_kernel(
    const ushort_t* __restrict__ qkv, ushort_t* __restrict__ out,
    const int* __restrict__ eff) {
  const int q = blockIdx.x, h = blockIdx.y, b = blockIdx.z;
  const int tid = threadIdx.x;
  __shared__ float sq[HDd];
  __shared__ float sc[Ss];
  __shared__ float rbuf[128];
  const size_t qbase = ((size_t)b * Ss + q) * (3 * Dm) + h * HDd;
  if (tid < HDd) sq[tid] = bf2f(qkv[qbase + tid]);
  __syncthreads();
  const int jmax = min(q, eff[b] - 1);
  float lmax = NEG_INF;
  for (int j = tid; j <= jmax; j += 128) {
    const unsigned int* kp = (const unsigned int*)(
        qkv + ((size_t)b * Ss + j) * (3 * Dm) + Dm + h * HDd);
    float d = 0.f;
#pragma unroll
    for (int x = 0; x < 32; x++) {
      const unsigned int u = kp[x];
      union { unsigned int i; float f; } lo, hi;
      lo.i = u << 16; hi.i = u & 0xffff0000u;
      d += lo.f * sq[2 * x] + hi.f * sq[2 * x + 1];
    }
    d *= 0.125f;
    sc[j] = d;
    lmax = fmaxf(lmax, d);
  }
  rbuf[tid] = lmax;
  __syncthreads();
  for (int k = 64; k > 0; k >>= 1) {
    if (tid < k) rbuf[tid] = fmaxf(rbuf[tid], rbuf[tid + k]);
    __syncthreads();
  }
  const float m = rbuf[0];
  __syncthreads();
  float lsum = 0.f;
  for (int j = tid; j <= jmax; j += 128) {
    const float p = expf(sc[j] - m);
    sc[j] = p;
    lsum += p;
  }
  rbuf[tid] = lsum;
  __syncthreads();
  for (int k = 64; k > 0; k >>= 1) {
    if (tid < k) rbuf[tid] += rbuf[tid + k];
    __syncthreads();
  }
  const float inv = 1.f / rbuf[0];
  __syncthreads();
  if (tid < HDd) {
    float acc = 0.f;
    const ushort_t* vp = qkv + (size_t)b * Ss * (3 * Dm) + 2 * Dm + h * HDd + tid;
    for (int j = 0; j <= jmax; j++) acc += sc[j] * bf2f(vp[(size_t)j * (3 * Dm)]);
    out[((size_t)b * Ss + q) * Dm + h * HDd + tid] = f2bf(acc * inv);
  }
}

// ---------------- log_softmax over 41, optional bf16 probs (padded to 64) ----------------
__global__ __launch_bounds__(64) void lsm41_kernel(
    const float* __restrict__ in, float* __restrict__ lp,
    ushort_t* __restrict__ probs) {
  const int row = blockIdx.x, t = threadIdx.x;
  const float z = (t < BLANK) ? in[(size_t)row * BLANK + t] : NEG_INF;
  float m = z;
#pragma unroll
  for (int off = 32; off; off >>= 1) m = fmaxf(m, __shfl_xor(m, off));
  float s = (t < BLANK) ? expf(z - m) : 0.f;
#pragma unroll
  for (int off = 32; off; off >>= 1) s += __shfl_xor(s, off);
  const float l = z - m - logf(s);
  if (t < BLANK) lp[(size_t)row * BLANK + t] = l;
  if (probs) probs[(size_t)row * 64 + t] = (t < BLANK) ? f2bf(expf(l)) : 0;
}

// ---------------- diphone marginalization ----------------
__global__ __launch_bounds__(64) void diphone_kernel(
    const float* __restrict__ in, float* __restrict__ out) {
  __shared__ float z[DIPd * DIPd];
  __shared__ float u[DIPd];
  const int row = blockIdx.x, t = threadIdx.x;
  for (int i = t; i < DIPd * DIPd; i += 64) z[i] = in[(size_t)row * (DIPd * DIPd) + i];
  __syncthreads();
  if (t < DIPd) {
    float m1 = NEG_INF;
    for (int j = 0; j < DIPd; j++) m1 = fmaxf(m1, z[t * DIPd + j]);
    float s1 = 0.f;
    for (int j = 0; j < DIPd; j++) s1 += expf(z[t * DIPd + j] - m1);
    const float lr = m1 + logf(s1);
    float m2 = NEG_INF;
    for (int j = 0; j < DIPd; j++) m2 = fmaxf(m2, z[j * DIPd + t]);
    float s2 = 0.f;
    for (int j = 0; j < DIPd; j++) s2 += expf(z[j * DIPd + t] - m2);
    const float lc = m2 + logf(s2);
    const float mx = fmaxf(lr, lc), mn = fminf(lr, lc);
    u[t] = mx + log1pf(expf(mn - mx));
  }
  __syncthreads();
  const float v = (t < DIPd) ? u[t] : NEG_INF;
  float m = v;
#pragma unroll
  for (int off = 32; off; off >>= 1) m = fmaxf(m, __shfl_xor(m, off));
  float s = (t < DIPd) ? expf(v - m) : 0.f;
#pragma unroll
  for (int off = 32; off; off >>= 1) s += __shfl_xor(s, off);
  const float lse = m + logf(s);
  if (t < DIPd) out[(size_t)row * DIPd + t] = v - lse;
}

__global__ void eff_kernel(const int* __restrict__ lengths, int* __restrict__ eff) {
  const int t = threadIdx.x;
  if (t < Bz) {
    int e = lengths[t] / KL;
    eff[t] = e < 1 ? 1 : e;
  }
}

// ---------------- host ----------------
extern "C" void kernel_launch(void* const* d_in, const int* in_sizes, int n_in,
                              void* d_out, int out_size, void* d_ws, size_t ws_size,
                              hipStream_t stream) {
  (void)in_sizes; (void)n_in; (void)out_size; (void)ws_size;
  const float* neural     = (const float*)d_in[0];
  const int*   lengths    = (const int*)d_in[1];
  const int*   day_idx    = (const int*)d_in[2];
  const float* day_W      = (const float*)d_in[3];
  const float* day_b      = (const float*)d_in[4];
  const float* pe_ln1_w   = (const float*)d_in[5];
  const float* pe_ln1_b   = (const float*)d_in[6];
  const float* pe_W       = (const float*)d_in[7];
  const float* pe_b       = (const float*)d_in[8];
  const float* pe_ln2_w   = (const float*)d_in[9];
  const float* pe_ln2_b   = (const float*)d_in[10];
  const float* ln_attn_w  = (const float*)d_in[11];
  const float* ln_attn_b  = (const float*)d_in[12];
  const float* qkv_W      = (const float*)d_in[13];
  const float* qkv_b      = (const float*)d_in[14];
  const float* attn_out_W = (const float*)d_in[15];
  const float* attn_out_b = (const float*)d_in[16];
  const float* ff_ln_w    = (const float*)d_in[17];
  const float* ff_ln_b    = (const float*)d_in[18];
  const float* fc1_W      = (const float*)d_in[19];
  const float* fc1_b      = (const float*)d_in[20];
  const float* fc2_W      = (const float*)d_in[21];
  const float* fc2_b      = (const float*)d_in[22];
  const float* final_ln_w = (const float*)d_in[23];
  const float* final_ln_b = (const float*)d_in[24];
  const float* ih_W       = (const float*)d_in[25];
  const float* ih_b       = (const float*)d_in[26];
  const float* fb_W       = (const float*)d_in[27];
  const float* fb_b       = (const float*)d_in[28];
  const float* fh_W       = (const float*)d_in[29];
  const float* fh_b       = (const float*)d_in[30];
  const float* dh_W       = (const float*)d_in[31];
  const float* dh_b       = (const float*)d_in[32];

  float* out = (float*)d_out;
  char* p = (char*)d_ws;

  float*    buf_x    = (float*)p;          p += 67117056;   // 8*8193*256 fp32
  ushort_t* buf_pein = (ushort_t*)p;                        // pe-LN out, later qkv
  ushort_t* buf_qkv  = (ushort_t*)p;       p += 33546240;   // 4680*3584 bf16
  float*    buf_h    = (float*)p;          p += 19169280;   // 4680*1024 fp32
  ushort_t* buf_abf  = (ushort_t*)p;       p += 9584640;    // 4680*1024 bf16
  ushort_t* buf_ao   = (ushort_t*)p;       p += 9584640;
  char*     ffp      = p;                  p += 38338560;   // 4680*4096 bf16
  ushort_t* wbuf     = (ushort_t*)p;       p += 25380864;   // 12,690,432 bf16
  int*      eff      = (int*)p;            p += 32;

  ushort_t* buf_ff   = (ushort_t*)ffp;
  float*    buf_dip  = (float*)ffp;                         // overlays (dead ff)
  float*    buf_blank= (float*)(ffp + 29952000);
  ushort_t* buf_probs= (ushort_t*)(ffp + 30719520);
  float*    buf_peout= buf_x;                               // overlays buf_x (dead)

  // wbuf element offsets
  ushort_t* qkvT = wbuf;                 // 3,145,728
  ushort_t* aoT  = wbuf + 3145728;       // 1,048,576
  ushort_t* fc1T = wbuf + 4194304;       // 4,194,304
  ushort_t* fc2T = wbuf + 8388608;       // 4,194,304
  ushort_t* ihT  = wbuf + 12582912;      // 41,984
  ushort_t* fbT  = wbuf + 12624896;      // 65,536
  ushort_t* peT  = wbuf;                 // pre-loop only (3,670,016)
  ushort_t* dhT  = wbuf;                 // post-loop (1,638,400)
  ushort_t* fhT  = wbuf + 1638400;       // post-loop (41,984)

  auto convt = [&](const float* in, ushort_t* o, int R, int C, int Rp) {
    dim3 g((Rp + 31) / 32, (C + 31) / 32);
    convt_kernel<<<g, dim3(32, 8), 0, stream>>>(in, o, R, C, Rp);
  };
  auto gemm = [&](const ushort_t* A, const ushort_t* Bt, const float* bias,
                  float* Cf, ushort_t* Cb, int M_, int N_, int K_, int epi) {
    dim3 g((M_ + BM - 1) / BM, (N_ + BN - 1) / BN);
    gemm_bf16<<<g, 256, 0, stream>>>(A, Bt, bias, Cf, Cb, M_, N_, K_, epi, eff);
  };

  eff_kernel<<<1, 64, 0, stream>>>(lengths, eff);
  smooth_kernel<<<dim3(TmD, Bz), 256, 0, stream>>>(neural, buf_x);
  day_kernel<<<dim3((TmD + 7) / 8, Bz), 256, 0, stream>>>(buf_x, day_W, day_b, day_idx, lengths);

  ln_kernel<<<MTOK, 256, 0, stream>>>(buf_x, pe_ln1_w, pe_ln1_b, nullptr, buf_pein,
                                      PEIN, 1e-6f, Ss, (long)TmD * NEU, (long)KL * NEU);
  convt(pe_W, peT, PEIN, Dm, PEIN);
  convt(ih_W, ihT, Dm, BLANK, Dm);
  convt(fb_W, fbT, BLANK, Dm, 64);
  gemm(buf_pein, peT, pe_b, buf_peout, nullptr, MTOK, Dm, PEIN, 0);
  ln_kernel<<<MTOK, 256, 0, stream>>>(buf_peout, pe_ln2_w, pe_ln2_b, buf_h, nullptr,
                                      Dm, 1e-6f, MTOK, 0L, (long)Dm);

  for (int i = 0; i < Ll; i++) {
    convt(qkv_W + (size_t)i * Dm * 3 * Dm, qkvT, Dm, 3 * Dm, Dm);
    convt(attn_out_W + (size_t)i * Dm * Dm, aoT, Dm, Dm, Dm);
    convt(fc1_W + (size_t)i * Dm * FFd, fc1T, Dm, FFd, Dm);
    convt(fc2_W + (size_t)i * FFd * Dm, fc2T, FFd, Dm, FFd);

    ln_kernel<<<MTOK, 256, 0, stream>>>(buf_h, ln_attn_w + (size_t)i * Dm,
                                        ln_attn_b + (size_t)i * Dm, nullptr, buf_abf,
                                        Dm, 1e-5f, MTOK, 0L, (long)Dm);
    gemm(buf_abf, qkvT, qkv_b + (size_t)i * 3 * Dm, nullptr, buf_qkv,
         MTOK, 3 * Dm, Dm, 4);
    attn_kernel<<<dim3(Ss, Hh, Bz), 128, 0, stream>>>(buf_qkv, buf_ao, eff);
    gemm(buf_ao, aoT, attn_out_b + (size_t)i * Dm, buf_h, nullptr,
         MTOK, Dm, Dm, 3);
    ln_kernel<<<MTOK, 256, 0, stream>>>(buf_h, ff_ln_w + (size_t)i * Dm,
                                        ff_ln_b + (size_t)i * Dm, nullptr, buf_abf,
                                        Dm, 1e-5f, MTOK, 0L, (long)Dm);
    gemm(buf_abf, fc1T, fc1_b + (size_t)i * FFd, nullptr, buf_ff,
         MTOK, FFd, Dm, 1);
    gemm(buf_ff, fc2T, fc2_b + (size_t)i * Dm, buf_h, nullptr,
         MTOK, Dm, FFd, 2);
    if (i == 3) {
      f2b_kernel<<<1024, 256, 0, stream>>>(buf_h, buf_abf, MTOK * Dm);
      gemm(buf_abf, ihT, ih_b, buf_blank, nullptr, MTOK, BLANK, Dm, 0);
      lsm41_kernel<<<MTOK, 64, 0, stream>>>(buf_blank, out + (size_t)MTOK * BLANK, buf_probs);
      gemm(buf_probs, fbT, fb_b, buf_h, nullptr, MTOK, Dm, 64, 2);
    }
  }

  ln_kernel<<<MTOK, 256, 0, stream>>>(buf_h, final_ln_w, final_ln_b, nullptr, buf_abf,
                                      Dm, 1e-5f, MTOK, 0L, (long)Dm);
  convt(dh_W, dhT, Dm, DIPd * DIPd, Dm);
  convt(fh_W, fhT, Dm, BLANK, Dm);
  gemm(buf_abf, fhT, fh_b, buf_blank, nullptr, MTOK, BLANK, Dm, 0);
  lsm41_kernel<<<MTOK, 64, 0, stream>>>(buf_blank, out, nullptr);
  gemm(buf_abf, dhT, dh_b, buf_dip, nullptr, MTOK, DIPd * DIPd, Dm, 0);
  diphone_kernel<<<MTOK, 64, 0, stream>>>(buf_dip, out + (size_t)2 * MTOK * BLANK);
}